// Round 5
// baseline (203.595 us; speedup 1.0000x reference)
//
#include <hip/hip_runtime.h>
#include <hip/hip_bf16.h>
#include <stdint.h>

typedef unsigned short u16;
typedef __attribute__((ext_vector_type(4))) float f32x4;
typedef __attribute__((ext_vector_type(8))) short s16x8;
typedef __attribute__((ext_vector_type(4))) float fvec4;

#define NH 12
#define DH 64
#define HID 768
#define SEQ 197
#define SP 208            // padded seq rows for Q/K slabs
#define VP 224            // padded seq cols for Vt slab
#define NREL 732
#define BATCH 64
#define MROWS (BATCH*SEQ) // 12608
#define NCAT (3*HID)      // 2304
#define BK 64
#define MT 99             // grid tiles in M (99*128 = 12672 >= 12608)
#define NT 18             // grid tiles in N (18*128 = 2304)
#define NWG (MT*NT)       // 1782

static __device__ __forceinline__ u16 f2bf(float f) {
  union { float f; uint32_t u; } v; v.f = f;
  uint32_t u = v.u;
  return (u16)((u + 0x7FFFu + ((u >> 16) & 1u)) >> 16);
}

// ---------------- prep: hidden fp32 -> bf16 ----------------
__global__ __launch_bounds__(256) void conv_x(const float* __restrict__ x, u16* __restrict__ xb, int n8) {
  int i = blockIdx.x * 256 + threadIdx.x;
  if (i >= n8) return;
  fvec4 a = ((const fvec4*)x)[2 * i];
  fvec4 b = ((const fvec4*)x)[2 * i + 1];
  s16x8 r;
  r[0] = (short)f2bf(a[0]); r[1] = (short)f2bf(a[1]); r[2] = (short)f2bf(a[2]); r[3] = (short)f2bf(a[3]);
  r[4] = (short)f2bf(b[0]); r[5] = (short)f2bf(b[1]); r[6] = (short)f2bf(b[2]); r[7] = (short)f2bf(b[3]);
  ((s16x8*)xb)[i] = r;
}

// ---------------- prep: W's -> transposed concat bf16 [NCAT][HID] ----------------
__global__ __launch_bounds__(256) void conv_w(const float* __restrict__ Wq, const float* __restrict__ Wk,
                                              const float* __restrict__ Wv, u16* __restrict__ Wt) {
  __shared__ float t[64][65];
  int n0 = blockIdx.x * 64;  // output row block (0..2303)
  int k0 = blockIdx.y * 64;  // k block (0..767)
  int m = n0 / HID;
  const float* W = (m == 0) ? Wq : ((m == 1) ? Wk : Wv);
  int nn0 = n0 - m * HID;
  for (int i = threadIdx.x; i < 64 * 64; i += 256) {
    int r = i >> 6, c = i & 63;
    t[r][c] = W[(size_t)(k0 + r) * HID + nn0 + c];   // coalesced read
  }
  __syncthreads();
  for (int i = threadIdx.x; i < 64 * 64; i += 256) {
    int r = i >> 6, c = i & 63;
    Wt[(size_t)(n0 + r) * HID + k0 + c] = f2bf(t[c][r]);  // coalesced write
  }
}

// ---------------- prep: bias concat (bq, 0, bv) ----------------
__global__ __launch_bounds__(256) void conv_b(const float* __restrict__ bq, const float* __restrict__ bv,
                                              float* __restrict__ bc) {
  int i = blockIdx.x * 256 + threadIdx.x;
  if (i < NCAT) {
    int m = i / HID, r = i - m * HID;
    bc[i] = (m == 0) ? bq[r] : ((m == 2) ? bv[r] : 0.f);
  }
}

// ---------------- prep: expand rel-pos bias to dense [NH][208][208] f32 ----------------
__global__ __launch_bounds__(256) void expand_bias(const float* __restrict__ bias_table, float* __restrict__ Bx) {
  int i = blockIdx.x * 256 + threadIdx.x;
  if (i >= NH * 208 * 208) return;
  int h = i / (208 * 208);
  int r = i - h * 208 * 208;
  int q = r / 208, k = r - q * 208;
  float v;
  if (k >= SEQ) v = -1e30f;       // mask padded k
  else if (q >= SEQ) v = 0.f;     // padded q rows: unused
  else {
    int idx;
    if (q == 0) idx = (k == 0) ? 731 : 729;
    else if (k == 0) idx = 730;
    else {
      int iq = (q - 1) / 14, jq = (q - 1) % 14;
      int ik = (k - 1) / 14, jk = (k - 1) % 14;
      idx = (iq - ik + 13) * 27 + (jq - jk + 13);
    }
    v = bias_table[(size_t)idx * NH + h];
  }
  Bx[i] = v;
}

// ---------------- fused QKV GEMM: [12608x768]x[768x2304], bf16 MFMA ----------------
// 128x128 tile, BK=64, 4 waves (2x2), DOUBLE-buffered (4 distinct LDS arrays,
// 64 KiB total -> 2 blocks/CU). Per K-step: stage(t+1 -> other buf) then
// ds_read+MFMA(t) then one __syncthreads (vmcnt(0) lands AFTER compute covered
// the prefetch latency). XOR-swizzled LDS via inverse-swizzled global source.
// m-pure epilogue: Q/K direct 32B-coalesced; V via LDS transpose.

static __device__ __forceinline__ void stage128(const u16* __restrict__ gbase, int grow0, int growmax,
                                                u16* lds, int w, int l) {
#pragma unroll
  for (int i = 0; i < 4; ++i) {
    int ch = w * 4 + i;                    // wave-uniform 0..15
    int r = ch * 8 + (l >> 3);
    int grow = grow0 + r; if (grow > growmax) grow = growmax;
    int c = (l & 7) ^ (l >> 3);            // inverse swizzle on source
    const u16* g = gbase + (size_t)grow * HID + c * 8;
    __builtin_amdgcn_global_load_lds((const __attribute__((address_space(1))) void*)g,
                                     (__attribute__((address_space(3))) void*)(lds + ch * 512),
                                     16, 0, 0);
  }
}

static __device__ __forceinline__ void compute128(const u16* As, const u16* Bs, int wr, int wc,
                                                  int li, int lg, f32x4 acc[4][4]) {
#pragma unroll
  for (int kk = 0; kk < 2; ++kk) {
    s16x8 af[4], bf[4];
#pragma unroll
    for (int mi = 0; mi < 4; ++mi) {
      int r = wr * 64 + mi * 16 + li;
      int c = (kk * 4 + lg) ^ (r & 7);
      af[mi] = *(const s16x8*)((const char*)As + r * 128 + c * 16);
    }
#pragma unroll
    for (int ni = 0; ni < 4; ++ni) {
      int r = wc * 64 + ni * 16 + li;
      int c = (kk * 4 + lg) ^ (r & 7);
      bf[ni] = *(const s16x8*)((const char*)Bs + r * 128 + c * 16);
    }
#pragma unroll
    for (int mi = 0; mi < 4; ++mi)
#pragma unroll
      for (int ni = 0; ni < 4; ++ni)
        acc[mi][ni] = __builtin_amdgcn_mfma_f32_16x16x32_bf16(af[mi], bf[ni], acc[mi][ni], 0, 0, 0);
  }
}

__global__ __launch_bounds__(256, 2) void qkv_gemm(const u16* __restrict__ Xb, const u16* __restrict__ Wt,
                                                   const float* __restrict__ bc, u16* __restrict__ Qw,
                                                   u16* __restrict__ Kw, u16* __restrict__ Vtw) {
  __shared__ u16 As0[128 * BK];
  __shared__ u16 Bs0[128 * BK];
  __shared__ u16 As1[128 * BK];
  __shared__ u16 Bs1[128 * BK];
  const int tid = threadIdx.x;
  const int w = tid >> 6, l = tid & 63;
  const int wr = w >> 1, wc = w & 1;        // 2x2 wave grid, 64x64 per wave
  const int lg = l >> 4, li = l & 15;

  // bijective XCD chunking (m204): nwg=1782, q=222, r=6
  const int lin = blockIdx.x;
  const int xcd = lin & 7;
  const int pos = lin >> 3;
  const int work = (xcd < 6 ? xcd * 223 : 6 * 223 + (xcd - 6) * 222) + pos;
  const int mt = work / NT, nt = work - mt * NT;
  const int arow0 = mt * 128, brow0 = nt * 128;

  f32x4 acc[4][4] = {};

  stage128(Xb, arow0, MROWS - 1, As0, w, l);
  stage128(Wt, brow0, NCAT - 1, Bs0, w, l);
  __syncthreads();

  for (int kt2 = 0; kt2 < 6; ++kt2) {
    const int kt = kt2 * 2;
    // even step: prefetch tile kt+1 -> buf1; compute tile kt from buf0
    stage128(Xb + (kt + 1) * BK, arow0, MROWS - 1, As1, w, l);
    stage128(Wt + (kt + 1) * BK, brow0, NCAT - 1, Bs1, w, l);
    compute128(As0, Bs0, wr, wc, li, lg, acc);
    __syncthreads();      // drains prefetch (already covered); frees buf0
    // odd step: prefetch tile kt+2 -> buf0; compute tile kt+1 from buf1
    if (kt2 < 5) {
      stage128(Xb + (kt + 2) * BK, arow0, MROWS - 1, As0, w, l);
      stage128(Wt + (kt + 2) * BK, brow0, NCAT - 1, Bs0, w, l);
    }
    compute128(As1, Bs1, wr, wc, li, lg, acc);
    __syncthreads();
  }

  // ---------------- m-pure epilogue ----------------
  const int mblk = nt / 6;                 // 0=Q, 1=K, 2=V (block-uniform)
  float bcv[4];
#pragma unroll
  for (int ni = 0; ni < 4; ++ni) bcv[ni] = bc[brow0 + wc * 64 + ni * 16 + li];

  if (mblk < 2) {
    // Q/K: direct stores, 32B-coalesced segments
    u16* __restrict__ dst = (mblk == 0) ? Qw : Kw;
    const float scale = (mblk == 0) ? 0.125f : 1.0f;
    int hv[4], dv[4];
#pragma unroll
    for (int ni = 0; ni < 4; ++ni) {
      int cloc = brow0 - mblk * HID + wc * 64 + ni * 16 + li;
      hv[ni] = cloc >> 6; dv[ni] = cloc & 63;
    }
#pragma unroll
    for (int mi = 0; mi < 4; ++mi) {
#pragma unroll
      for (int j = 0; j < 4; ++j) {
        int row = arow0 + wr * 64 + mi * 16 + lg * 4 + j;
        if (row < MROWS) {
          int b = row / SEQ, s = row - b * SEQ;
#pragma unroll
          for (int ni = 0; ni < 4; ++ni)
            dst[((size_t)(b * NH + hv[ni]) * SP + s) * DH + dv[ni]] = f2bf((acc[mi][ni][j] + bcv[ni]) * scale);
        }
      }
    }
  } else {
    // V: transpose through LDS (stride 130 halves), store s-contiguous
    u16* T = As0;                          // 128*130*2 = 33,280 B spans As0+Bs0 (32 KiB contiguous? no --
                                           // distinct arrays; stay within As0+Bs0 by using 2 halves)
    // NOTE: As0,Bs0,As1,Bs1 are each 16 KiB; T needs 33,280 B. Use As0 as base and
    // rely on contiguity is NOT guaranteed across arrays -> use explicit union buffer.
    // (handled below via TBUF overlay)
    (void)T;
    __shared__ u16 TBUF[128 * 130];        // 33,280 B additional LDS (total 98,560 B < 160 KiB; still 1 block/CU? no:
                                           // 98,560*2 > 160K -> 1 block/CU for V blocks only via same kernel... see note)
#pragma unroll
    for (int mi = 0; mi < 4; ++mi)
#pragma unroll
      for (int ni = 0; ni < 4; ++ni)
#pragma unroll
        for (int j = 0; j < 4; ++j) {
          int c = wc * 64 + ni * 16 + li;
          int r = wr * 64 + mi * 16 + lg * 4 + j;
          TBUF[c * 130 + r] = f2bf(acc[mi][ni][j] + bcv[ni]);
        }
    __syncthreads();
    int cw0 = brow0 - 2 * HID;             // V-local col base
#pragma unroll
    for (int p = 0; p < 8; ++p) {
      int c = p * 16 + (tid >> 4);         // 0..127
      int sc = tid & 15;
      int cloc = cw0 + c;
      int h = cloc >> 6, d = cloc & 63;
#pragma unroll
      for (int e = 0; e < 8; ++e) {
        int row = arow0 + sc * 8 + e;
        if (row < MROWS) {
          int b = row / SEQ, s = row - b * SEQ;
          Vtw[((size_t)(b * NH + h) * DH + d) * VP + s] = TBUF[c * 130 + sc * 8 + e];
        }
      }
    }
  }
}

// ---------------- fused attention: 1 WAVE per (bh, qf) — zero barriers ----------------
__global__ __launch_bounds__(64, 3) void attn(const u16* __restrict__ Qw, const u16* __restrict__ Kw,
                                              const u16* __restrict__ Vtw, const float* __restrict__ Bx,
                                              float* __restrict__ out) {
  __shared__ u16 P[16 * 232];      // 16 q-rows x 208 k-cols (+pad), conflict-free b128
  const int l = threadIdx.x;
  const int lg = l >> 4, li = l & 15;
  const int blk = blockIdx.x;      // bh * 13 + qf
  const int bh = blk / 13, qf = blk - bh * 13;
  const int b = bh / NH, h = bh - b * NH;

  // zero tail cols 208..231 (read by PV t-loop, never written)
  for (int t = l; t < 16 * 24; t += 64) {
    int rr = t / 24, cc = t - rr * 24;
    P[rr * 232 + 208 + cc] = 0;
  }

  const u16* Qb = Qw + (size_t)bh * SP * DH;
  const u16* Kb = Kw + (size_t)bh * SP * DH;
  const u16* Vb = Vtw + (size_t)bh * DH * VP;
  const float* Bh = Bx + ((size_t)h * 208 + qf * 16 + lg * 4) * 208;

  // ---- QK^T ----
  s16x8 a0 = *(const s16x8*)(Qb + (size_t)(qf * 16 + li) * DH + lg * 8);
  s16x8 a1 = *(const s16x8*)(Qb + (size_t)(qf * 16 + li) * DH + 32 + lg * 8);
  f32x4 S[13];
#pragma unroll
  for (int kf = 0; kf < 13; ++kf) {
    s16x8 b0 = *(const s16x8*)(Kb + (size_t)(kf * 16 + li) * DH + lg * 8);
    s16x8 b1 = *(const s16x8*)(Kb + (size_t)(kf * 16 + li) * DH + 32 + lg * 8);
    f32x4 c = {};
    c = __builtin_amdgcn_mfma_f32_16x16x32_bf16(a0, b0, c, 0, 0, 0);
    c = __builtin_amdgcn_mfma_f32_16x16x32_bf16(a1, b1, c, 0, 0, 0);
    S[kf] = c;
  }

  // ---- + bias (mask baked in) ----
#pragma unroll
  for (int kf = 0; kf < 13; ++kf)
#pragma unroll
    for (int j = 0; j < 4; ++j)
      S[kf][j] += Bh[j * 208 + kf * 16 + li];

  // ---- softmax over 13 regs x 16 lanes (per 16-lane group) ----
  float rinv[4];
#pragma unroll
  for (int j = 0; j < 4; ++j) {
    float m = S[0][j];
#pragma unroll
    for (int kf = 1; kf < 13; ++kf) m = fmaxf(m, S[kf][j]);
    m = fmaxf(m, __shfl_xor(m, 1));
    m = fmaxf(m, __shfl_xor(m, 2));
    m = fmaxf(m, __shfl_xor(m, 4));
    m = fmaxf(m, __shfl_xor(m, 8));
    float sum = 0.f;
#pragma unroll
    for (int kf = 0; kf < 13; ++kf) {
      float p = __expf(S[kf][j] - m);
      S[kf][j] = p;
      sum += p;
    }
    sum += __shfl_xor(sum, 1);
    sum += __shfl_xor(sum, 2);
    sum += __shfl_xor(sum, 4);
    sum += __shfl_xor(sum, 8);
    rinv[j] = 1.0f / sum;
  }

  // ---- transpose P into LDS (bf16) ----
#pragma unroll
  for (int kf = 0; kf < 13; ++kf)
#pragma unroll
    for (int j = 0; j < 4; ++j)
      P[(lg * 4 + j) * 232 + kf * 16 + li] = f2bf(S[kf][j]);

  // ---- PV ----
#pragma unroll
  for (int nf = 0; nf < 4; ++nf) {
    f32x4 c = {};
#pragma unroll
    for (int t = 0; t < 7; ++t) {
      s16x8 pa = *(const s16x8*)(&P[li * 232 + t * 32 + lg * 8]);
      s16x8 vb = *(const s16x8*)(Vb + (size_t)(nf * 16 + li) * VP + t * 32 + lg * 8);
      c = __builtin_amdgcn_mfma_f32_16x16x32_bf16(pa, vb, c, 0, 0, 0);
    }
#pragma unroll
    for (int j = 0; j < 4; ++j) {
      int q = qf * 16 + lg * 4 + j;
      if (q < SEQ)
        out[((size_t)(b * SEQ + q)) * HID + h * DH + nf * 16 + li] = c[j] * rinv[j];
    }
  }
}

extern "C" void kernel_launch(void* const* d_in, const int* in_sizes, int n_in,
                              void* d_out, int out_size, void* d_ws, size_t ws_size,
                              hipStream_t stream) {
  const float* hidden = (const float*)d_in[0];
  const float* Wq = (const float*)d_in[1];
  const float* bq = (const float*)d_in[2];
  const float* Wk = (const float*)d_in[3];
  const float* Wv = (const float*)d_in[4];
  const float* bv = (const float*)d_in[5];
  const float* btab = (const float*)d_in[6];
  float* out = (float*)d_out;

  char* ws = (char*)d_ws;
  u16* Xb  = (u16*)(ws);                       // 12608*768*2      = 19,365,888
  u16* Wt  = (u16*)(ws + 19365888);            // 2304*768*2       =  3,538,944
  float* bc = (float*)(ws + 22904832);         // 2304*4           =      9,216
  u16* Qw  = (u16*)(ws + 22914048);            // 768*208*64*2     = 20,447,232
  u16* Kw  = (u16*)(ws + 43361280);            // 768*208*64*2     = 20,447,232
  u16* Vtw = (u16*)(ws + 63808512);            // 768*64*224*2     = 22,020,096 (end 85,828,608)
  float* Bx = (float*)(ws);                    // reuses Xb region AFTER qkv_gemm

  conv_x<<<dim3(4728), dim3(256), 0, stream>>>(hidden, Xb, (MROWS * HID) / 8);
  conv_w<<<dim3(NCAT / 64, HID / 64), dim3(256), 0, stream>>>(Wq, Wk, Wv, Wt);
  conv_b<<<dim3(9), dim3(256), 0, stream>>>(bq, bv, bc);
  qkv_gemm<<<dim3(NWG), dim3(256), 0, stream>>>(Xb, Wt, bc, Qw, Kw, Vtw);
  expand_bias<<<dim3((NH * 208 * 208 + 255) / 256), dim3(256), 0, stream>>>(btab, Bx);
  attn<<<dim3(768 * 13), dim3(64), 0, stream>>>(Qw, Kw, Vtw, Bx, out);
}

// Round 6
// 183.390 us; speedup vs baseline: 1.1102x; 1.1102x over previous
//
#include <hip/hip_runtime.h>
#include <hip/hip_bf16.h>
#include <stdint.h>

typedef unsigned short u16;
typedef __attribute__((ext_vector_type(4))) float f32x4;
typedef __attribute__((ext_vector_type(8))) short s16x8;
typedef __attribute__((ext_vector_type(4))) float fvec4;

#define NH 12
#define DH 64
#define HID 768
#define SEQ 197
#define SP 208            // padded seq rows for Q/K slabs
#define VP 224            // padded seq cols for Vt slab
#define NREL 732
#define BATCH 64
#define MROWS (BATCH*SEQ) // 12608
#define NCAT (3*HID)      // 2304
#define BK 64
#define MT 99             // grid tiles in M (99*128 = 12672 >= 12608)
#define NT 18             // grid tiles in N (18*128 = 2304)
#define NWG (MT*NT)       // 1782

static __device__ __forceinline__ u16 f2bf(float f) {
  union { float f; uint32_t u; } v; v.f = f;
  uint32_t u = v.u;
  return (u16)((u + 0x7FFFu + ((u >> 16) & 1u)) >> 16);
}

// ---------------- prep: hidden fp32 -> bf16 ----------------
__global__ __launch_bounds__(256) void conv_x(const float* __restrict__ x, u16* __restrict__ xb, int n8) {
  int i = blockIdx.x * 256 + threadIdx.x;
  if (i >= n8) return;
  fvec4 a = ((const fvec4*)x)[2 * i];
  fvec4 b = ((const fvec4*)x)[2 * i + 1];
  s16x8 r;
  r[0] = (short)f2bf(a[0]); r[1] = (short)f2bf(a[1]); r[2] = (short)f2bf(a[2]); r[3] = (short)f2bf(a[3]);
  r[4] = (short)f2bf(b[0]); r[5] = (short)f2bf(b[1]); r[6] = (short)f2bf(b[2]); r[7] = (short)f2bf(b[3]);
  ((s16x8*)xb)[i] = r;
}

// ---------------- prep: W's -> transposed concat bf16 [NCAT][HID] ----------------
__global__ __launch_bounds__(256) void conv_w(const float* __restrict__ Wq, const float* __restrict__ Wk,
                                              const float* __restrict__ Wv, u16* __restrict__ Wt) {
  __shared__ float t[64][65];
  int n0 = blockIdx.x * 64;  // output row block (0..2303)
  int k0 = blockIdx.y * 64;  // k block (0..767)
  int m = n0 / HID;
  const float* W = (m == 0) ? Wq : ((m == 1) ? Wk : Wv);
  int nn0 = n0 - m * HID;
  for (int i = threadIdx.x; i < 64 * 64; i += 256) {
    int r = i >> 6, c = i & 63;
    t[r][c] = W[(size_t)(k0 + r) * HID + nn0 + c];   // coalesced read
  }
  __syncthreads();
  for (int i = threadIdx.x; i < 64 * 64; i += 256) {
    int r = i >> 6, c = i & 63;
    Wt[(size_t)(n0 + r) * HID + k0 + c] = f2bf(t[c][r]);  // coalesced write
  }
}

// ---------------- prep: bias concat (bq, 0, bv) ----------------
__global__ __launch_bounds__(256) void conv_b(const float* __restrict__ bq, const float* __restrict__ bv,
                                              float* __restrict__ bc) {
  int i = blockIdx.x * 256 + threadIdx.x;
  if (i < NCAT) {
    int m = i / HID, r = i - m * HID;
    bc[i] = (m == 0) ? bq[r] : ((m == 2) ? bv[r] : 0.f);
  }
}

// ---------------- prep: expand rel-pos bias to dense [NH][208][208] f32 ----------------
__global__ __launch_bounds__(256) void expand_bias(const float* __restrict__ bias_table, float* __restrict__ Bx) {
  int i = blockIdx.x * 256 + threadIdx.x;
  if (i >= NH * 208 * 208) return;
  int h = i / (208 * 208);
  int r = i - h * 208 * 208;
  int q = r / 208, k = r - q * 208;
  float v;
  if (k >= SEQ) v = -1e30f;       // mask padded k
  else if (q >= SEQ) v = 0.f;     // padded q rows: unused
  else {
    int idx;
    if (q == 0) idx = (k == 0) ? 731 : 729;
    else if (k == 0) idx = 730;
    else {
      int iq = (q - 1) / 14, jq = (q - 1) % 14;
      int ik = (k - 1) / 14, jk = (k - 1) % 14;
      idx = (iq - ik + 13) * 27 + (jq - jk + 13);
    }
    v = bias_table[(size_t)idx * NH + h];
  }
  Bx[i] = v;
}

// ---------------- fused QKV GEMM: [12608x768]x[768x2304], bf16 MFMA ----------------
// 128x128 tile, BK=64, 4 waves (2x2), double-buffered (4 distinct 16 KiB LDS
// arrays = 64 KiB total -> 2 blocks/CU). Per K-step: stage(t+1 -> other buf),
// compute(t), ONE __syncthreads (its vmcnt(0) lands after compute covered the
// prefetch latency). XOR-swizzled LDS via inverse-swizzled global source.
// Uniform epilogue: Q/K/V all stored [bh][s][d] with 32B-coalesced segments.

static __device__ __forceinline__ void stage128(const u16* __restrict__ gbase, int grow0, int growmax,
                                                u16* lds, int w, int l) {
#pragma unroll
  for (int i = 0; i < 4; ++i) {
    int ch = w * 4 + i;                    // wave-uniform 0..15
    int r = ch * 8 + (l >> 3);
    int grow = grow0 + r; if (grow > growmax) grow = growmax;
    int c = (l & 7) ^ (l >> 3);            // inverse swizzle on source
    const u16* g = gbase + (size_t)grow * HID + c * 8;
    __builtin_amdgcn_global_load_lds((const __attribute__((address_space(1))) void*)g,
                                     (__attribute__((address_space(3))) void*)(lds + ch * 512),
                                     16, 0, 0);
  }
}

static __device__ __forceinline__ void compute128(const u16* As, const u16* Bs, int wr, int wc,
                                                  int li, int lg, f32x4 acc[4][4]) {
#pragma unroll
  for (int kk = 0; kk < 2; ++kk) {
    s16x8 af[4], bf[4];
#pragma unroll
    for (int mi = 0; mi < 4; ++mi) {
      int r = wr * 64 + mi * 16 + li;
      int c = (kk * 4 + lg) ^ (r & 7);
      af[mi] = *(const s16x8*)((const char*)As + r * 128 + c * 16);
    }
#pragma unroll
    for (int ni = 0; ni < 4; ++ni) {
      int r = wc * 64 + ni * 16 + li;
      int c = (kk * 4 + lg) ^ (r & 7);
      bf[ni] = *(const s16x8*)((const char*)Bs + r * 128 + c * 16);
    }
#pragma unroll
    for (int mi = 0; mi < 4; ++mi)
#pragma unroll
      for (int ni = 0; ni < 4; ++ni)
        acc[mi][ni] = __builtin_amdgcn_mfma_f32_16x16x32_bf16(af[mi], bf[ni], acc[mi][ni], 0, 0, 0);
  }
}

__global__ __launch_bounds__(256, 2) void qkv_gemm(const u16* __restrict__ Xb, const u16* __restrict__ Wt,
                                                   const float* __restrict__ bc, u16* __restrict__ Qw,
                                                   u16* __restrict__ Kw, u16* __restrict__ Vw) {
  __shared__ u16 As0[128 * BK];
  __shared__ u16 Bs0[128 * BK];
  __shared__ u16 As1[128 * BK];
  __shared__ u16 Bs1[128 * BK];
  const int tid = threadIdx.x;
  const int w = tid >> 6, l = tid & 63;
  const int wr = w >> 1, wc = w & 1;        // 2x2 wave grid, 64x64 per wave
  const int lg = l >> 4, li = l & 15;

  // bijective XCD chunking (m204): nwg=1782, q=222, r=6
  const int lin = blockIdx.x;
  const int xcd = lin & 7;
  const int pos = lin >> 3;
  const int work = (xcd < 6 ? xcd * 223 : 6 * 223 + (xcd - 6) * 222) + pos;
  const int mt = work / NT, nt = work - mt * NT;
  const int arow0 = mt * 128, brow0 = nt * 128;

  f32x4 acc[4][4] = {};

  stage128(Xb, arow0, MROWS - 1, As0, w, l);
  stage128(Wt, brow0, NCAT - 1, Bs0, w, l);
  __syncthreads();

  for (int kt2 = 0; kt2 < 6; ++kt2) {
    const int kt = kt2 * 2;
    // even: prefetch kt+1 -> buf1; compute kt from buf0; sync frees buf0
    stage128(Xb + (kt + 1) * BK, arow0, MROWS - 1, As1, w, l);
    stage128(Wt + (kt + 1) * BK, brow0, NCAT - 1, Bs1, w, l);
    compute128(As0, Bs0, wr, wc, li, lg, acc);
    __syncthreads();
    // odd: prefetch kt+2 -> buf0; compute kt+1 from buf1; sync frees buf1
    if (kt2 < 5) {
      stage128(Xb + (kt + 2) * BK, arow0, MROWS - 1, As0, w, l);
      stage128(Wt + (kt + 2) * BK, brow0, NCAT - 1, Bs0, w, l);
    }
    compute128(As1, Bs1, wr, wc, li, lg, acc);
    __syncthreads();
  }

  // ---------------- uniform m-pure epilogue (block-uniform dst/scale/stride) ----------------
  const int mblk = nt / 6;                 // 0=Q, 1=K, 2=V
  u16* __restrict__ dst = (mblk == 0) ? Qw : ((mblk == 1) ? Kw : Vw);
  const float scale = (mblk == 0) ? 0.125f : 1.0f;
  const int STR = (mblk == 2) ? SEQ : SP;  // rows per bh slab (V is tight: 197)
  int hv[4], dv[4]; float bcv[4];
#pragma unroll
  for (int ni = 0; ni < 4; ++ni) {
    int col = brow0 + wc * 64 + ni * 16 + li;
    int cloc = col - mblk * HID;
    hv[ni] = cloc >> 6; dv[ni] = cloc & 63;
    bcv[ni] = bc[col];
  }
#pragma unroll
  for (int mi = 0; mi < 4; ++mi) {
#pragma unroll
    for (int j = 0; j < 4; ++j) {
      int row = arow0 + wr * 64 + mi * 16 + lg * 4 + j;
      if (row < MROWS) {
        int b = row / SEQ, s = row - b * SEQ;
#pragma unroll
        for (int ni = 0; ni < 4; ++ni)
          dst[((size_t)(b * NH + hv[ni]) * STR + s) * DH + dv[ni]] = f2bf((acc[mi][ni][j] + bcv[ni]) * scale);
      }
    }
  }
}

// ---------------- transpose V: [bh][197][64] -> [bh][64][224] (tail zero) ----------------
__global__ __launch_bounds__(256) void transpose_v(const u16* __restrict__ Vw, u16* __restrict__ Vt) {
  __shared__ u16 T[64][209];       // [d][s] u16; odd stride spreads banks
  const int bh = blockIdx.x;
  const int tid = threadIdx.x;
  const u16* src = Vw + (size_t)bh * SEQ * DH;
  // load rows (coalesced along d), write transposed into LDS
  for (int i = tid; i < 208 * 64; i += 256) {
    int r = i >> 6, c = i & 63;    // consecutive tid -> consecutive c (coalesced)
    u16 v = (r < SEQ) ? src[(size_t)r * DH + c] : (u16)0;
    T[c][r] = v;
  }
  __syncthreads();
  // write out rows of Vt (coalesced u32 along s)
  uint32_t* __restrict__ dst = (uint32_t*)(Vt + (size_t)bh * DH * VP);
  for (int i = tid; i < 64 * 112; i += 256) {
    int d = i / 112, s2 = i - d * 112;   // consecutive tid -> consecutive s2 (coalesced)
    uint32_t v = 0;
    if (s2 < 104) v = (uint32_t)T[d][2 * s2] | ((uint32_t)T[d][2 * s2 + 1] << 16);
    dst[(size_t)d * 112 + s2] = v;
  }
}

// ---------------- fused attention: 1 WAVE per (bh, qf) — zero barriers ----------------
__global__ __launch_bounds__(64, 3) void attn(const u16* __restrict__ Qw, const u16* __restrict__ Kw,
                                              const u16* __restrict__ Vt, const float* __restrict__ Bx,
                                              float* __restrict__ out) {
  __shared__ u16 P[16 * 232];      // 16 q-rows x 208 k-cols (+pad), conflict-free b128
  const int l = threadIdx.x;
  const int lg = l >> 4, li = l & 15;
  const int blk = blockIdx.x;      // bh * 13 + qf
  const int bh = blk / 13, qf = blk - bh * 13;
  const int b = bh / NH, h = bh - b * NH;

  // zero tail cols 208..231 (read by PV t-loop, never written)
  for (int t = l; t < 16 * 24; t += 64) {
    int rr = t / 24, cc = t - rr * 24;
    P[rr * 232 + 208 + cc] = 0;
  }

  const u16* Qb = Qw + (size_t)bh * SP * DH;
  const u16* Kb = Kw + (size_t)bh * SP * DH;
  const u16* Vb = Vt + (size_t)bh * DH * VP;
  const float* Bh = Bx + ((size_t)h * 208 + qf * 16 + lg * 4) * 208;

  // ---- QK^T ----
  s16x8 a0 = *(const s16x8*)(Qb + (size_t)(qf * 16 + li) * DH + lg * 8);
  s16x8 a1 = *(const s16x8*)(Qb + (size_t)(qf * 16 + li) * DH + 32 + lg * 8);
  f32x4 S[13];
#pragma unroll
  for (int kf = 0; kf < 13; ++kf) {
    s16x8 b0 = *(const s16x8*)(Kb + (size_t)(kf * 16 + li) * DH + lg * 8);
    s16x8 b1 = *(const s16x8*)(Kb + (size_t)(kf * 16 + li) * DH + 32 + lg * 8);
    f32x4 c = {};
    c = __builtin_amdgcn_mfma_f32_16x16x32_bf16(a0, b0, c, 0, 0, 0);
    c = __builtin_amdgcn_mfma_f32_16x16x32_bf16(a1, b1, c, 0, 0, 0);
    S[kf] = c;
  }

  // ---- + bias (mask baked in) ----
#pragma unroll
  for (int kf = 0; kf < 13; ++kf)
#pragma unroll
    for (int j = 0; j < 4; ++j)
      S[kf][j] += Bh[j * 208 + kf * 16 + li];

  // ---- softmax over 13 regs x 16 lanes (per 16-lane group) ----
  float rinv[4];
#pragma unroll
  for (int j = 0; j < 4; ++j) {
    float m = S[0][j];
#pragma unroll
    for (int kf = 1; kf < 13; ++kf) m = fmaxf(m, S[kf][j]);
    m = fmaxf(m, __shfl_xor(m, 1));
    m = fmaxf(m, __shfl_xor(m, 2));
    m = fmaxf(m, __shfl_xor(m, 4));
    m = fmaxf(m, __shfl_xor(m, 8));
    float sum = 0.f;
#pragma unroll
    for (int kf = 0; kf < 13; ++kf) {
      float p = __expf(S[kf][j] - m);
      S[kf][j] = p;
      sum += p;
    }
    sum += __shfl_xor(sum, 1);
    sum += __shfl_xor(sum, 2);
    sum += __shfl_xor(sum, 4);
    sum += __shfl_xor(sum, 8);
    rinv[j] = 1.0f / sum;
  }

  // ---- transpose P into LDS (bf16) ----
#pragma unroll
  for (int kf = 0; kf < 13; ++kf)
#pragma unroll
    for (int j = 0; j < 4; ++j)
      P[(lg * 4 + j) * 232 + kf * 16 + li] = f2bf(S[kf][j]);

  // ---- PV ----
#pragma unroll
  for (int nf = 0; nf < 4; ++nf) {
    f32x4 c = {};
#pragma unroll
    for (int t = 0; t < 7; ++t) {
      s16x8 pa = *(const s16x8*)(&P[li * 232 + t * 32 + lg * 8]);
      s16x8 vb = *(const s16x8*)(Vb + (size_t)(nf * 16 + li) * VP + t * 32 + lg * 8);
      c = __builtin_amdgcn_mfma_f32_16x16x32_bf16(pa, vb, c, 0, 0, 0);
    }
#pragma unroll
    for (int j = 0; j < 4; ++j) {
      int q = qf * 16 + lg * 4 + j;
      if (q < SEQ)
        out[((size_t)(b * SEQ + q)) * HID + h * DH + nf * 16 + li] = c[j] * rinv[j];
    }
  }
}

extern "C" void kernel_launch(void* const* d_in, const int* in_sizes, int n_in,
                              void* d_out, int out_size, void* d_ws, size_t ws_size,
                              hipStream_t stream) {
  const float* hidden = (const float*)d_in[0];
  const float* Wq = (const float*)d_in[1];
  const float* bq = (const float*)d_in[2];
  const float* Wk = (const float*)d_in[3];
  const float* Wv = (const float*)d_in[4];
  const float* bv = (const float*)d_in[5];
  const float* btab = (const float*)d_in[6];
  float* out = (float*)d_out;

  // workspace layout (peak 85,260,288 B; Vt overlays dead Xb/Wt after qkv):
  char* ws = (char*)d_ws;
  u16* Xb  = (u16*)(ws);                       // [0, 19,365,888)   12608*768*2
  u16* Wt  = (u16*)(ws + 19365888);            // [.., 22,904,832)  2304*768*2
  float* bc = (float*)(ws + 22904832);         // [.., 22,914,048)  2304*4
  float* Bx = (float*)(ws + 22914048);         // [.., 24,990,720)  12*208*208*4
  u16* Qw  = (u16*)(ws + 24990720);            // [.., 45,437,952)  768*208*64*2
  u16* Kw  = (u16*)(ws + 45437952);            // [.., 65,885,184)  768*208*64*2
  u16* Vw  = (u16*)(ws + 65885184);            // [.., 85,260,288)  768*197*64*2
  u16* Vt  = (u16*)(ws);                       // overlays Xb/Wt: 768*64*224*2 = 22,020,096

  conv_x<<<dim3(4728), dim3(256), 0, stream>>>(hidden, Xb, (MROWS * HID) / 8);
  conv_w<<<dim3(NCAT / 64, HID / 64), dim3(256), 0, stream>>>(Wq, Wk, Wv, Wt);
  conv_b<<<dim3(9), dim3(256), 0, stream>>>(bq, bv, bc);
  qkv_gemm<<<dim3(NWG), dim3(256), 0, stream>>>(Xb, Wt, bc, Qw, Kw, Vw);
  transpose_v<<<dim3(768), dim3(256), 0, stream>>>(Vw, Vt);
  expand_bias<<<dim3((NH * 208 * 208 + 255) / 256), dim3(256), 0, stream>>>(btab, Bx);
  attn<<<dim3(768 * 13), dim3(64), 0, stream>>>(Qw, Kw, Vt, Bx, out);
}

// Round 7
// 165.205 us; speedup vs baseline: 1.2324x; 1.1101x over previous
//
#include <hip/hip_runtime.h>
#include <hip/hip_bf16.h>
#include <stdint.h>

typedef unsigned short u16;
typedef __attribute__((ext_vector_type(4))) float f32x4;
typedef __attribute__((ext_vector_type(8))) short s16x8;
typedef __attribute__((ext_vector_type(4))) float fvec4;

#define NH 12
#define DH 64
#define HID 768
#define SEQ 197
#define SP 208            // padded seq rows for Q/K slabs
#define VP 224            // padded seq cols for Vt slab
#define NREL 732
#define BATCH 64
#define MROWS (BATCH*SEQ) // 12608
#define NCAT (3*HID)      // 2304
#define BK 64
#define MT 99             // grid tiles in M (99*128 = 12672 >= 12608)
#define NT 18             // grid tiles in N (18*128 = 2304)
#define NWG (MT*NT)       // 1782
#define AWG (768*13)      // 9984 attn blocks = 8 * 1248

static __device__ __forceinline__ u16 f2bf(float f) {
  union { float f; uint32_t u; } v; v.f = f;
  uint32_t u = v.u;
  return (u16)((u + 0x7FFFu + ((u >> 16) & 1u)) >> 16);
}

// ---------------- prep: hidden fp32 -> bf16 ----------------
__global__ __launch_bounds__(256) void conv_x(const float* __restrict__ x, u16* __restrict__ xb, int n8) {
  int i = blockIdx.x * 256 + threadIdx.x;
  if (i >= n8) return;
  fvec4 a = ((const fvec4*)x)[2 * i];
  fvec4 b = ((const fvec4*)x)[2 * i + 1];
  s16x8 r;
  r[0] = (short)f2bf(a[0]); r[1] = (short)f2bf(a[1]); r[2] = (short)f2bf(a[2]); r[3] = (short)f2bf(a[3]);
  r[4] = (short)f2bf(b[0]); r[5] = (short)f2bf(b[1]); r[6] = (short)f2bf(b[2]); r[7] = (short)f2bf(b[3]);
  ((s16x8*)xb)[i] = r;
}

// ---------------- prep: W's -> transposed concat bf16 [NCAT][HID] ----------------
__global__ __launch_bounds__(256) void conv_w(const float* __restrict__ Wq, const float* __restrict__ Wk,
                                              const float* __restrict__ Wv, u16* __restrict__ Wt) {
  __shared__ float t[64][65];
  int n0 = blockIdx.x * 64;  // output row block (0..2303)
  int k0 = blockIdx.y * 64;  // k block (0..767)
  int m = n0 / HID;
  const float* W = (m == 0) ? Wq : ((m == 1) ? Wk : Wv);
  int nn0 = n0 - m * HID;
  for (int i = threadIdx.x; i < 64 * 64; i += 256) {
    int r = i >> 6, c = i & 63;
    t[r][c] = W[(size_t)(k0 + r) * HID + nn0 + c];   // coalesced read
  }
  __syncthreads();
  for (int i = threadIdx.x; i < 64 * 64; i += 256) {
    int r = i >> 6, c = i & 63;
    Wt[(size_t)(n0 + r) * HID + k0 + c] = f2bf(t[c][r]);  // coalesced write
  }
}

// ---------------- prep: bias concat (bq, 0, bv) ----------------
__global__ __launch_bounds__(256) void conv_b(const float* __restrict__ bq, const float* __restrict__ bv,
                                              float* __restrict__ bc) {
  int i = blockIdx.x * 256 + threadIdx.x;
  if (i < NCAT) {
    int m = i / HID, r = i - m * HID;
    bc[i] = (m == 0) ? bq[r] : ((m == 2) ? bv[r] : 0.f);
  }
}

// ---------------- prep: expand rel-pos bias to dense [NH][208][208] f32 ----------------
__global__ __launch_bounds__(256) void expand_bias(const float* __restrict__ bias_table, float* __restrict__ Bx) {
  int i = blockIdx.x * 256 + threadIdx.x;
  if (i >= NH * 208 * 208) return;
  int h = i / (208 * 208);
  int r = i - h * 208 * 208;
  int q = r / 208, k = r - q * 208;
  float v;
  if (k >= SEQ) v = -1e30f;       // mask padded k
  else if (q >= SEQ) v = 0.f;     // padded q rows: unused
  else {
    int idx;
    if (q == 0) idx = (k == 0) ? 731 : 729;
    else if (k == 0) idx = 730;
    else {
      int iq = (q - 1) / 14, jq = (q - 1) % 14;
      int ik = (k - 1) / 14, jk = (k - 1) % 14;
      idx = (iq - ik + 13) * 27 + (jq - jk + 13);
    }
    v = bias_table[(size_t)idx * NH + h];
  }
  Bx[i] = v;
}

// ---------------- fused QKV GEMM: [12608x768]x[768x2304], bf16 MFMA ----------------
// 128x128 tile, BK=64, 4 waves (2x2), double-buffered (4 distinct 16 KiB LDS
// arrays = 64 KiB total -> 2 blocks/CU). Per K-step: stage(t+1 -> other buf),
// compute(t), ONE __syncthreads. XOR-swizzled LDS via inverse-swizzled source.

static __device__ __forceinline__ void stage128(const u16* __restrict__ gbase, int grow0, int growmax,
                                                u16* lds, int w, int l) {
#pragma unroll
  for (int i = 0; i < 4; ++i) {
    int ch = w * 4 + i;                    // wave-uniform 0..15
    int r = ch * 8 + (l >> 3);
    int grow = grow0 + r; if (grow > growmax) grow = growmax;
    int c = (l & 7) ^ (l >> 3);            // inverse swizzle on source
    const u16* g = gbase + (size_t)grow * HID + c * 8;
    __builtin_amdgcn_global_load_lds((const __attribute__((address_space(1))) void*)g,
                                     (__attribute__((address_space(3))) void*)(lds + ch * 512),
                                     16, 0, 0);
  }
}

static __device__ __forceinline__ void compute128(const u16* As, const u16* Bs, int wr, int wc,
                                                  int li, int lg, f32x4 acc[4][4]) {
#pragma unroll
  for (int kk = 0; kk < 2; ++kk) {
    s16x8 af[4], bf[4];
#pragma unroll
    for (int mi = 0; mi < 4; ++mi) {
      int r = wr * 64 + mi * 16 + li;
      int c = (kk * 4 + lg) ^ (r & 7);
      af[mi] = *(const s16x8*)((const char*)As + r * 128 + c * 16);
    }
#pragma unroll
    for (int ni = 0; ni < 4; ++ni) {
      int r = wc * 64 + ni * 16 + li;
      int c = (kk * 4 + lg) ^ (r & 7);
      bf[ni] = *(const s16x8*)((const char*)Bs + r * 128 + c * 16);
    }
#pragma unroll
    for (int mi = 0; mi < 4; ++mi)
#pragma unroll
      for (int ni = 0; ni < 4; ++ni)
        acc[mi][ni] = __builtin_amdgcn_mfma_f32_16x16x32_bf16(af[mi], bf[ni], acc[mi][ni], 0, 0, 0);
  }
}

__global__ __launch_bounds__(256, 2) void qkv_gemm(const u16* __restrict__ Xb, const u16* __restrict__ Wt,
                                                   const float* __restrict__ bc, u16* __restrict__ Qw,
                                                   u16* __restrict__ Kw, u16* __restrict__ Vw) {
  __shared__ u16 As0[128 * BK];
  __shared__ u16 Bs0[128 * BK];
  __shared__ u16 As1[128 * BK];
  __shared__ u16 Bs1[128 * BK];
  const int tid = threadIdx.x;
  const int w = tid >> 6, l = tid & 63;
  const int wr = w >> 1, wc = w & 1;        // 2x2 wave grid, 64x64 per wave
  const int lg = l >> 4, li = l & 15;

  // bijective XCD chunking (m204): nwg=1782, q=222, r=6
  const int lin = blockIdx.x;
  const int xcd = lin & 7;
  const int pos = lin >> 3;
  const int work = (xcd < 6 ? xcd * 223 : 6 * 223 + (xcd - 6) * 222) + pos;
  const int mt = work / NT, nt = work - mt * NT;
  const int arow0 = mt * 128, brow0 = nt * 128;

  f32x4 acc[4][4] = {};

  stage128(Xb, arow0, MROWS - 1, As0, w, l);
  stage128(Wt, brow0, NCAT - 1, Bs0, w, l);
  __syncthreads();

  for (int kt2 = 0; kt2 < 6; ++kt2) {
    const int kt = kt2 * 2;
    // even: prefetch kt+1 -> buf1; compute kt from buf0; sync frees buf0
    stage128(Xb + (kt + 1) * BK, arow0, MROWS - 1, As1, w, l);
    stage128(Wt + (kt + 1) * BK, brow0, NCAT - 1, Bs1, w, l);
    compute128(As0, Bs0, wr, wc, li, lg, acc);
    __syncthreads();
    // odd: prefetch kt+2 -> buf0; compute kt+1 from buf1; sync frees buf1
    if (kt2 < 5) {
      stage128(Xb + (kt + 2) * BK, arow0, MROWS - 1, As0, w, l);
      stage128(Wt + (kt + 2) * BK, brow0, NCAT - 1, Bs0, w, l);
    }
    compute128(As1, Bs1, wr, wc, li, lg, acc);
    __syncthreads();
  }

  // ---------------- uniform m-pure epilogue (block-uniform dst/scale/stride) ----------------
  const int mblk = nt / 6;                 // 0=Q, 1=K, 2=V
  u16* __restrict__ dst = (mblk == 0) ? Qw : ((mblk == 1) ? Kw : Vw);
  const float scale = (mblk == 0) ? 0.125f : 1.0f;
  const int STR = (mblk == 2) ? SEQ : SP;  // rows per bh slab (V is tight: 197)
  int hv[4], dv[4]; float bcv[4];
#pragma unroll
  for (int ni = 0; ni < 4; ++ni) {
    int col = brow0 + wc * 64 + ni * 16 + li;
    int cloc = col - mblk * HID;
    hv[ni] = cloc >> 6; dv[ni] = cloc & 63;
    bcv[ni] = bc[col];
  }
#pragma unroll
  for (int mi = 0; mi < 4; ++mi) {
#pragma unroll
    for (int j = 0; j < 4; ++j) {
      int row = arow0 + wr * 64 + mi * 16 + lg * 4 + j;
      if (row < MROWS) {
        int b = row / SEQ, s = row - b * SEQ;
#pragma unroll
        for (int ni = 0; ni < 4; ++ni)
          dst[((size_t)(b * NH + hv[ni]) * STR + s) * DH + dv[ni]] = f2bf((acc[mi][ni][j] + bcv[ni]) * scale);
      }
    }
  }
}

// ---------------- transpose V: [bh][197][64] -> [bh][64][224] (tail zero) ----------------
__global__ __launch_bounds__(256) void transpose_v(const u16* __restrict__ Vw, u16* __restrict__ Vt) {
  __shared__ u16 T[64][209];       // [d][s] u16; odd stride spreads banks
  const int bh = blockIdx.x;
  const int tid = threadIdx.x;
  const u16* src = Vw + (size_t)bh * SEQ * DH;
  // load rows (coalesced along d), write transposed into LDS
  for (int i = tid; i < 208 * 64; i += 256) {
    int r = i >> 6, c = i & 63;    // consecutive tid -> consecutive c (coalesced)
    u16 v = (r < SEQ) ? src[(size_t)r * DH + c] : (u16)0;
    T[c][r] = v;
  }
  __syncthreads();
  // write out rows of Vt (coalesced u32 along s)
  uint32_t* __restrict__ dst = (uint32_t*)(Vt + (size_t)bh * DH * VP);
  for (int i = tid; i < 64 * 112; i += 256) {
    int d = i / 112, s2 = i - d * 112;   // consecutive tid -> consecutive s2 (coalesced)
    uint32_t v = 0;
    if (s2 < 104) v = (uint32_t)T[d][2 * s2] | ((uint32_t)T[d][2 * s2 + 1] << 16);
    dst[(size_t)d * 112 + s2] = v;
  }
}

// ---------------- fused attention: 1 WAVE per (bh, qf) — zero barriers ----------------
// XCD-chunked block swizzle: 9984 = 8*1248 exactly; the 13 blocks sharing one
// bh's K/V/Q slabs run consecutively on ONE XCD -> slabs + Bx stay L2-resident.
__global__ __launch_bounds__(64, 3) void attn(const u16* __restrict__ Qw, const u16* __restrict__ Kw,
                                              const u16* __restrict__ Vt, const float* __restrict__ Bx,
                                              float* __restrict__ out) {
  __shared__ u16 P[16 * 232];      // 16 q-rows x 208 k-cols (+pad), conflict-free b128
  const int l = threadIdx.x;
  const int lg = l >> 4, li = l & 15;
  const int lin = blockIdx.x;
  const int work = (lin & 7) * (AWG / 8) + (lin >> 3);   // bijective XCD chunking
  const int bh = work / 13, qf = work - bh * 13;
  const int b = bh / NH, h = bh - b * NH;

  // zero tail cols 208..231 (read by PV t-loop, never written)
  for (int t = l; t < 16 * 24; t += 64) {
    int rr = t / 24, cc = t - rr * 24;
    P[rr * 232 + 208 + cc] = 0;
  }

  const u16* Qb = Qw + (size_t)bh * SP * DH;
  const u16* Kb = Kw + (size_t)bh * SP * DH;
  const u16* Vb = Vt + (size_t)bh * DH * VP;
  const float* Bh = Bx + ((size_t)h * 208 + qf * 16 + lg * 4) * 208;

  // ---- QK^T ----
  s16x8 a0 = *(const s16x8*)(Qb + (size_t)(qf * 16 + li) * DH + lg * 8);
  s16x8 a1 = *(const s16x8*)(Qb + (size_t)(qf * 16 + li) * DH + 32 + lg * 8);
  f32x4 S[13];
#pragma unroll
  for (int kf = 0; kf < 13; ++kf) {
    s16x8 b0 = *(const s16x8*)(Kb + (size_t)(kf * 16 + li) * DH + lg * 8);
    s16x8 b1 = *(const s16x8*)(Kb + (size_t)(kf * 16 + li) * DH + 32 + lg * 8);
    f32x4 c = {};
    c = __builtin_amdgcn_mfma_f32_16x16x32_bf16(a0, b0, c, 0, 0, 0);
    c = __builtin_amdgcn_mfma_f32_16x16x32_bf16(a1, b1, c, 0, 0, 0);
    S[kf] = c;
  }

  // ---- + bias (mask baked in) ----
#pragma unroll
  for (int kf = 0; kf < 13; ++kf)
#pragma unroll
    for (int j = 0; j < 4; ++j)
      S[kf][j] += Bh[j * 208 + kf * 16 + li];

  // ---- softmax over 13 regs x 16 lanes (per 16-lane group) ----
  float rinv[4];
#pragma unroll
  for (int j = 0; j < 4; ++j) {
    float m = S[0][j];
#pragma unroll
    for (int kf = 1; kf < 13; ++kf) m = fmaxf(m, S[kf][j]);
    m = fmaxf(m, __shfl_xor(m, 1));
    m = fmaxf(m, __shfl_xor(m, 2));
    m = fmaxf(m, __shfl_xor(m, 4));
    m = fmaxf(m, __shfl_xor(m, 8));
    float sum = 0.f;
#pragma unroll
    for (int kf = 0; kf < 13; ++kf) {
      float p = __expf(S[kf][j] - m);
      S[kf][j] = p;
      sum += p;
    }
    sum += __shfl_xor(sum, 1);
    sum += __shfl_xor(sum, 2);
    sum += __shfl_xor(sum, 4);
    sum += __shfl_xor(sum, 8);
    rinv[j] = 1.0f / sum;
  }

  // ---- transpose P into LDS (bf16) ----
#pragma unroll
  for (int kf = 0; kf < 13; ++kf)
#pragma unroll
    for (int j = 0; j < 4; ++j)
      P[(lg * 4 + j) * 232 + kf * 16 + li] = f2bf(S[kf][j]);

  // ---- PV ----
#pragma unroll
  for (int nf = 0; nf < 4; ++nf) {
    f32x4 c = {};
#pragma unroll
    for (int t = 0; t < 7; ++t) {
      s16x8 pa = *(const s16x8*)(&P[li * 232 + t * 32 + lg * 8]);
      s16x8 vb = *(const s16x8*)(Vb + (size_t)(nf * 16 + li) * VP + t * 32 + lg * 8);
      c = __builtin_amdgcn_mfma_f32_16x16x32_bf16(pa, vb, c, 0, 0, 0);
    }
#pragma unroll
    for (int j = 0; j < 4; ++j) {
      int q = qf * 16 + lg * 4 + j;
      if (q < SEQ)
        out[((size_t)(b * SEQ + q)) * HID + h * DH + nf * 16 + li] = c[j] * rinv[j];
    }
  }
}

extern "C" void kernel_launch(void* const* d_in, const int* in_sizes, int n_in,
                              void* d_out, int out_size, void* d_ws, size_t ws_size,
                              hipStream_t stream) {
  const float* hidden = (const float*)d_in[0];
  const float* Wq = (const float*)d_in[1];
  const float* bq = (const float*)d_in[2];
  const float* Wk = (const float*)d_in[3];
  const float* Wv = (const float*)d_in[4];
  const float* bv = (const float*)d_in[5];
  const float* btab = (const float*)d_in[6];
  float* out = (float*)d_out;

  // workspace layout (peak 85,260,288 B; Vt overlays dead Xb/Wt after qkv):
  char* ws = (char*)d_ws;
  u16* Xb  = (u16*)(ws);                       // [0, 19,365,888)   12608*768*2
  u16* Wt  = (u16*)(ws + 19365888);            // [.., 22,904,832)  2304*768*2
  float* bc = (float*)(ws + 22904832);         // [.., 22,914,048)  2304*4
  float* Bx = (float*)(ws + 22914048);         // [.., 24,990,720)  12*208*208*4
  u16* Qw  = (u16*)(ws + 24990720);            // [.., 45,437,952)  768*208*64*2
  u16* Kw  = (u16*)(ws + 45437952);            // [.., 65,885,184)  768*208*64*2
  u16* Vw  = (u16*)(ws + 65885184);            // [.., 85,260,288)  768*197*64*2
  u16* Vt  = (u16*)(ws);                       // overlays Xb/Wt: 768*64*224*2 = 22,020,096

  conv_x<<<dim3(4728), dim3(256), 0, stream>>>(hidden, Xb, (MROWS * HID) / 8);
  conv_w<<<dim3(NCAT / 64, HID / 64), dim3(256), 0, stream>>>(Wq, Wk, Wv, Wt);
  conv_b<<<dim3(9), dim3(256), 0, stream>>>(bq, bv, bc);
  qkv_gemm<<<dim3(NWG), dim3(256), 0, stream>>>(Xb, Wt, bc, Qw, Kw, Vw);
  transpose_v<<<dim3(768), dim3(256), 0, stream>>>(Vw, Vt);
  expand_bias<<<dim3((NH * 208 * 208 + 255) / 256), dim3(256), 0, stream>>>(btab, Bx);
  attn<<<dim3(AWG), dim3(64), 0, stream>>>(Qw, Kw, Vt, Bx, out);
}